// Round 1
// baseline (8423.624 us; speedup 1.0000x reference)
//
#include <hip/hip_runtime.h>
#include <math.h>

#define NB 64
#define NN 16
#define H 128
#define SSTEPS 3
#define NE 131072
#define NT 5
#define NCELL 16384
#define NCLU 1088
#define LIN_W 768   // (T+1)*H
#define G4 512      // 4*H
#define EB 64       // edges per block in edge kernel

// ---------------- avg of class embeddings 1..16 per batch ----------------
__global__ __launch_bounds__(128) void k_avg(const float* __restrict__ emb,
                                             float* __restrict__ avg) {
    int b = blockIdx.x, hc = threadIdx.x;
    float s = 0.f;
#pragma unroll
    for (int r = 1; r <= 16; ++r) s += emb[(b * 17 + r) * H + hc];
    avg[b * H + hc] = s * (1.0f / 16.0f);
}

// ---------------- init: cell_x -> lstm_in[:,0:128] & hx; rnn_h=c=0 ----------------
__global__ __launch_bounds__(256) void k_init(const int* __restrict__ q,
                                              const float* __restrict__ emb,
                                              const float* __restrict__ avg,
                                              float* __restrict__ lstm_in,
                                              float* __restrict__ hx,
                                              float* __restrict__ rnn_h,
                                              float* __restrict__ cst) {
    int idx = blockIdx.x * 256 + threadIdx.x;  // NCELL*32 float4s
    int row = idx >> 5, v = idx & 31;
    int b = row >> 8;
    int qi = q[row];
    const float* src = (qi == 0) ? (avg + b * H) : (emb + (b * 17 + qi) * H);
    float4 val = reinterpret_cast<const float4*>(src)[v];
    reinterpret_cast<float4*>(lstm_in + (size_t)row * LIN_W)[v] = val;
    reinterpret_cast<float4*>(hx + (size_t)row * H)[v] = val;
    float4 z4 = make_float4(0.f, 0.f, 0.f, 0.f);
    reinterpret_cast<float4*>(rnn_h + (size_t)row * H)[v] = z4;
    reinterpret_cast<float4*>(cst + (size_t)row * H)[v] = z4;
}

// ---------------- zero the message columns of lstm_in ----------------
__global__ __launch_bounds__(256) void k_zeromsg(float* __restrict__ lstm_in) {
    int idx = blockIdx.x * 256 + threadIdx.x;  // NCELL*160 float4s
    int row = idx / 160, cc = idx % 160;
    reinterpret_cast<float4*>(lstm_in + (size_t)row * LIN_W + H)[cc] =
        make_float4(0.f, 0.f, 0.f, 0.f);
}

// ---------------- generic fp32 tiled GEMM: C[64bx][64by] tiles ----------------
// C = A[M,K](lda) @ B[K,N](ldb) (+C if accumulate). M%64==0 (grid.x), N%64==0 (grid.y), K%32==0.
__global__ __launch_bounds__(256) void k_gemm(const float* __restrict__ A, int lda,
                                              const float* __restrict__ B, int ldb,
                                              float* __restrict__ C, int ldc,
                                              int K, int accumulate) {
    __shared__ float As[64][33];
    __shared__ float Bs[32][64];
    int tid = threadIdx.x;
    int ty = tid >> 4, tx = tid & 15;
    int rbase = blockIdx.x * 64, cbase = blockIdx.y * 64;
    float acc[4][4] = {};
    for (int k0 = 0; k0 < K; k0 += 32) {
        __syncthreads();
#pragma unroll
        for (int i = 0; i < 8; ++i) {   // stage A 64x32
            int id = tid + i * 256;
            int r = id >> 5, c = id & 31;
            As[r][c] = A[(size_t)(rbase + r) * lda + k0 + c];
        }
#pragma unroll
        for (int i = 0; i < 8; ++i) {   // stage B 32x64
            int id = tid + i * 256;
            int r = id >> 6, c = id & 63;
            Bs[r][c] = B[(size_t)(k0 + r) * ldb + cbase + c];
        }
        __syncthreads();
#pragma unroll 8
        for (int kk = 0; kk < 32; ++kk) {
            float a[4], bv[4];
#pragma unroll
            for (int i = 0; i < 4; ++i) a[i] = As[ty * 4 + i][kk];
#pragma unroll
            for (int j = 0; j < 4; ++j) bv[j] = Bs[kk][tx * 4 + j];
#pragma unroll
            for (int i = 0; i < 4; ++i)
#pragma unroll
                for (int j = 0; j < 4; ++j) acc[i][j] = fmaf(a[i], bv[j], acc[i][j]);
        }
    }
#pragma unroll
    for (int i = 0; i < 4; ++i) {
        int r = rbase + ty * 4 + i;
#pragma unroll
        for (int j = 0; j < 4; ++j) {
            int c = cbase + tx * 4 + j;
            float v = acc[i][j];
            if (accumulate) v += C[(size_t)r * ldc + c];
            C[(size_t)r * ldc + c] = v;
        }
    }
}

// ---------------- fused per-edge MLP (layers 2..4) ----------------
__device__ __forceinline__ void mlp_accum(const float (*z)[132], float (*Ws)[132],
                                          const float* __restrict__ Wg,
                                          int ty, int tx, int tid, float acc[4][8]) {
#pragma unroll 1
    for (int chunk = 0; chunk < 2; ++chunk) {
        __syncthreads();
        const float* wg = Wg + chunk * 64 * H;
#pragma unroll
        for (int i = 0; i < 8; ++i) {   // stage 64x128 W-rows chunk
            int id = tid + i * 256;     // 2048 float4
            int r = id >> 5, c4 = id & 31;
            float4 wv = *reinterpret_cast<const float4*>(wg + r * H + c4 * 4);
            *reinterpret_cast<float4*>(&Ws[r][c4 * 4]) = wv;
        }
        __syncthreads();
        int kb = chunk * 64;
#pragma unroll 8
        for (int kk = 0; kk < 64; ++kk) {
            float a[4], bv[8];
#pragma unroll
            for (int i = 0; i < 4; ++i) a[i] = z[ty * 4 + i][kb + kk];
#pragma unroll
            for (int j = 0; j < 8; ++j) bv[j] = Ws[kk][tx * 8 + j];
#pragma unroll
            for (int i = 0; i < 4; ++i)
#pragma unroll
                for (int j = 0; j < 8; ++j) acc[i][j] = fmaf(a[i], bv[j], acc[i][j]);
        }
    }
    __syncthreads();   // all reads of z done before caller overwrites it
}

__global__ __launch_bounds__(256) void k_edge(const int* __restrict__ edges,
                                              const float* __restrict__ P,
                                              const float* __restrict__ Ps0,
                                              const float* __restrict__ W2,
                                              const float* __restrict__ b2,
                                              const float* __restrict__ W3,
                                              const float* __restrict__ b3,
                                              const float* __restrict__ W4,
                                              const float* __restrict__ b4,
                                              const float* __restrict__ b1,
                                              float* __restrict__ lstm_in) {
    __shared__ float z[EB][132];
    __shared__ float Ws[64][132];
    __shared__ int ssrc[EB], sdst[EB];
    int tid = threadIdx.x;
    int bid = blockIdx.x;
    int t = bid >> 11;           // NE/EB == 2048 tiles per type
    int tile = bid & 2047;

    if (tid < EB) {
        int e = tile * EB + tid;
        ssrc[tid] = edges[(t * 2 + 0) * NE + e];
        sdst[tid] = edges[(t * 2 + 1) * NE + e];
    }
    __syncthreads();

    // layer 1: z = relu(Ps[src] + Pd[dst] + b1)
    {
        int e = tid >> 2, part = tid & 3;
        const float* ps = (t == 0) ? (Ps0 + (size_t)ssrc[e] * H)
                                   : (P + (size_t)ssrc[e] * 1152 + 640 + (t - 1) * H);
        const float* pd = P + (size_t)sdst[e] * 1152 + t * H;
        const float* bb = b1 + t * H;
#pragma unroll
        for (int i = 0; i < 8; ++i) {
            int v = i * 4 + part;   // float4 index 0..31
            float4 a = reinterpret_cast<const float4*>(ps)[v];
            float4 d = reinterpret_cast<const float4*>(pd)[v];
            float4 bi = reinterpret_cast<const float4*>(bb)[v];
            float* zp = &z[e][v * 4];
            zp[0] = fmaxf(a.x + d.x + bi.x, 0.f);
            zp[1] = fmaxf(a.y + d.y + bi.y, 0.f);
            zp[2] = fmaxf(a.z + d.z + bi.z, 0.f);
            zp[3] = fmaxf(a.w + d.w + bi.w, 0.f);
        }
    }
    int ty = tid >> 4, tx = tid & 15;   // rows ty*4..+3, cols tx*8..+7

    // layer 2 (relu)
    {
        float acc[4][8] = {};
        mlp_accum(z, Ws, W2 + t * 16384, ty, tx, tid, acc);
        const float* bb = b2 + t * H;
#pragma unroll
        for (int i = 0; i < 4; ++i)
#pragma unroll
            for (int j = 0; j < 8; ++j)
                z[ty * 4 + i][tx * 8 + j] = fmaxf(acc[i][j] + bb[tx * 8 + j], 0.f);
    }
    // layer 3 (relu)
    {
        float acc[4][8] = {};
        mlp_accum(z, Ws, W3 + t * 16384, ty, tx, tid, acc);
        const float* bb = b3 + t * H;
#pragma unroll
        for (int i = 0; i < 4; ++i)
#pragma unroll
            for (int j = 0; j < 8; ++j)
                z[ty * 4 + i][tx * 8 + j] = fmaxf(acc[i][j] + bb[tx * 8 + j], 0.f);
    }
    // layer 4 (no relu) + scatter-add
    {
        float acc[4][8] = {};
        mlp_accum(z, Ws, W4 + t * 16384, ty, tx, tid, acc);
        const float* bb = b4 + t * H;
#pragma unroll
        for (int i = 0; i < 4; ++i) {
            int d = sdst[ty * 4 + i];
            float* outp = lstm_in + (size_t)d * LIN_W + H + t * H + tx * 8;
#pragma unroll
            for (int j = 0; j < 8; ++j)
                atomicAdd(outp + j, acc[i][j] + bb[tx * 8 + j]);
        }
    }
}

// ---------------- LSTM pointwise ----------------
__global__ __launch_bounds__(256) void k_lstm(const float* __restrict__ gates,
                                              float* __restrict__ cst,
                                              float* __restrict__ rnn_h) {
    int idx = blockIdx.x * 256 + threadIdx.x;   // NCELL*H
    int row = idx >> 7, cc = idx & 127;
    const float* g = gates + (size_t)row * G4;
    float ig = g[cc], fg = g[128 + cc], gg = g[256 + cc], og = g[384 + cc];
    float c_old = cst[idx];
    float i_s = 1.f / (1.f + expf(-ig));
    float f_s = 1.f / (1.f + expf(-fg));
    float o_s = 1.f / (1.f + expf(-og));
    float c_new = f_s * c_old + i_s * tanhf(gg);
    float h_new = o_s * tanhf(c_new);
    cst[idx] = c_new;
    rnn_h[idx] = h_new;
}

// ---------------- logits: per (batch) block, 256 rows x 17 classes ----------------
__global__ __launch_bounds__(256) void k_logits(const float* __restrict__ h,
                                                const float* __restrict__ oemb,
                                                float* __restrict__ out) {
    __shared__ float oe[17][129];
    int b = blockIdx.x, tid = threadIdx.x;
    for (int id = tid; id < 17 * 128; id += 256) {
        int r = id >> 7, c = id & 127;
        oe[r][c] = oemb[(b * 17 + r) * H + c];
    }
    __syncthreads();
    const float* hr = h + (size_t)(b * 256 + tid) * H;
    float acc[17] = {};
    for (int v = 0; v < 32; ++v) {
        float4 hv = reinterpret_cast<const float4*>(hr)[v];
#pragma unroll
        for (int cls = 0; cls < 17; ++cls) {
            acc[cls] = fmaf(hv.x, oe[cls][v * 4 + 0],
                       fmaf(hv.y, oe[cls][v * 4 + 1],
                       fmaf(hv.z, oe[cls][v * 4 + 2],
                       fmaf(hv.w, oe[cls][v * 4 + 3], acc[cls]))));
        }
    }
    float* op = out + (size_t)(b * 256 + tid) * 17;
#pragma unroll
    for (int cls = 0; cls < 17; ++cls) op[cls] = acc[cls];
}

extern "C" void kernel_launch(void* const* d_in, const int* in_sizes, int n_in,
                              void* d_out, int out_size, void* d_ws, size_t ws_size,
                              hipStream_t stream) {
    (void)in_sizes; (void)n_in; (void)out_size; (void)ws_size;
    const int*   edges = (const int*)d_in[0];
    const int*   q     = (const int*)d_in[1];
    const float* emb   = (const float*)d_in[2];
    const float* oemb  = (const float*)d_in[3];
    const float* W1    = (const float*)d_in[4];
    const float* b1    = (const float*)d_in[5];
    const float* W2    = (const float*)d_in[6];
    const float* b2    = (const float*)d_in[7];
    const float* W3    = (const float*)d_in[8];
    const float* b3    = (const float*)d_in[9];
    const float* W4    = (const float*)d_in[10];
    const float* b4    = (const float*)d_in[11];
    const float* Wih   = (const float*)d_in[12];
    const float* Whh   = (const float*)d_in[13];
    float* out = (float*)d_out;

    float* ws      = (float*)d_ws;
    float* lstm_in = ws;                              // 16384*768
    float* hx      = lstm_in + (size_t)NCELL * LIN_W; // 16384*128
    float* rnn_h   = hx + (size_t)NCELL * H;
    float* cst     = rnn_h + (size_t)NCELL * H;
    float* P       = cst + (size_t)NCELL * H;         // 16384*1152
    float* gates   = P;                               // alias (P dead when gates live)
    float* Ps0     = P + (size_t)NCELL * 1152;        // 1088*128
    float* avg     = Ps0 + (size_t)NCLU * H;          // 64*128

    k_avg<<<64, 128, 0, stream>>>(emb, avg);
    k_init<<<2048, 256, 0, stream>>>(q, emb, avg, lstm_in, hx, rnn_h, cst);
    // Ps0 = input_embeddings @ W1s_0  (cluster states are constant)
    {
        dim3 g0(17, 2);
        k_gemm<<<g0, 256, 0, stream>>>(emb, H, W1, H, Ps0, H, H, 0);
    }

    for (int s = 0; s < SSTEPS; ++s) {
        k_zeromsg<<<10240, 256, 0, stream>>>(lstm_in);
        const float* hcur = (s == 0) ? hx : rnn_h;
        dim3 gp(256, 2);
        // Pd_t = h @ W1d_t  -> P[:, t*128 : ]
        for (int t = 0; t < 5; ++t)
            k_gemm<<<gp, 256, 0, stream>>>(hcur, H, W1 + t * 32768 + 16384, H,
                                           P + t * 128, 1152, H, 0);
        // Ps_t = h @ W1s_t (t>=1) -> P[:, 640+(t-1)*128 : ]
        for (int t = 1; t < 5; ++t)
            k_gemm<<<gp, 256, 0, stream>>>(hcur, H, W1 + t * 32768, H,
                                           P + 640 + (t - 1) * 128, 1152, H, 0);
        k_edge<<<NT * (NE / EB), 256, 0, stream>>>(edges, P, Ps0, W2, b2, W3, b3,
                                                   W4, b4, b1, lstm_in);
        dim3 gg(256, 8);
        k_gemm<<<gg, 256, 0, stream>>>(lstm_in, LIN_W, Wih, G4, gates, G4, LIN_W, 0);
        if (s > 0)
            k_gemm<<<gg, 256, 0, stream>>>(rnn_h, H, Whh, G4, gates, G4, H, 1);
        k_lstm<<<8192, 256, 0, stream>>>(gates, cst, rnn_h);
        k_logits<<<64, 256, 0, stream>>>(rnn_h, oemb, out + (size_t)s * NCELL * 17);
    }
}

// Round 2
// 2623.751 us; speedup vs baseline: 3.2105x; 3.2105x over previous
//
#include <hip/hip_runtime.h>
#include <math.h>

#define NB 64
#define H 128
#define SSTEPS 3
#define NE 131072
#define NT 5
#define NCELL 16384
#define NCLU 1088
#define LIN_W 768   // (T+1)*H
#define G4 512      // 4*H
#define EB 128      // edges per block in edge kernel

typedef unsigned short u16;
typedef __attribute__((ext_vector_type(8))) short short8;
typedef __attribute__((ext_vector_type(8))) unsigned short ushort8;
typedef __attribute__((ext_vector_type(4))) float f32x4;

__device__ __forceinline__ u16 f2bf(float f) {
    unsigned int u = __float_as_uint(f);
    u += 0x7fffu + ((u >> 16) & 1u);
    return (u16)(u >> 16);
}
__device__ __forceinline__ float bf2f(u16 h) {
    return __uint_as_float(((unsigned int)h) << 16);
}

// ---------------- avg of class embeddings 1..16 per batch ----------------
__global__ __launch_bounds__(128) void k_avg(const float* __restrict__ emb,
                                             float* __restrict__ avg) {
    int b = blockIdx.x, hc = threadIdx.x;
    float s = 0.f;
#pragma unroll
    for (int r = 1; r <= 16; ++r) s += emb[(b * 17 + r) * H + hc];
    avg[b * H + hc] = s * (1.0f / 16.0f);
}

// ---------------- init: cell_x -> lstm_in[:,0:128] & hx; rnn_h=c=0 ----------------
__global__ __launch_bounds__(256) void k_init(const int* __restrict__ q,
                                              const float* __restrict__ emb,
                                              const float* __restrict__ avg,
                                              float* __restrict__ lstm_in,
                                              float* __restrict__ hx,
                                              float* __restrict__ rnn_h,
                                              float* __restrict__ cst) {
    int idx = blockIdx.x * 256 + threadIdx.x;  // NCELL*32 float4s
    int row = idx >> 5, v = idx & 31;
    int b = row >> 8;
    int qi = q[row];
    const float* src = (qi == 0) ? (avg + b * H) : (emb + (b * 17 + qi) * H);
    float4 val = reinterpret_cast<const float4*>(src)[v];
    reinterpret_cast<float4*>(lstm_in + (size_t)row * LIN_W)[v] = val;
    reinterpret_cast<float4*>(hx + (size_t)row * H)[v] = val;
    float4 z4 = make_float4(0.f, 0.f, 0.f, 0.f);
    reinterpret_cast<float4*>(rnn_h + (size_t)row * H)[v] = z4;
    reinterpret_cast<float4*>(cst + (size_t)row * H)[v] = z4;
}

// ---------------- zero the message columns of lstm_in ----------------
__global__ __launch_bounds__(256) void k_zeromsg(float* __restrict__ lstm_in) {
    int idx = blockIdx.x * 256 + threadIdx.x;  // NCELL*160 float4s
    int row = idx / 160, cc = idx % 160;
    reinterpret_cast<float4*>(lstm_in + (size_t)row * LIN_W + H)[cc] =
        make_float4(0.f, 0.f, 0.f, 0.f);
}

// ---------------- generic fp32 tiled GEMM ----------------
__global__ __launch_bounds__(256) void k_gemm(const float* __restrict__ A, int lda,
                                              const float* __restrict__ B, int ldb,
                                              float* __restrict__ C, int ldc,
                                              int K, int accumulate) {
    __shared__ float As[64][33];
    __shared__ float Bs[32][64];
    int tid = threadIdx.x;
    int ty = tid >> 4, tx = tid & 15;
    int rbase = blockIdx.x * 64, cbase = blockIdx.y * 64;
    float acc[4][4] = {};
    for (int k0 = 0; k0 < K; k0 += 32) {
        __syncthreads();
#pragma unroll
        for (int i = 0; i < 8; ++i) {
            int id = tid + i * 256;
            int r = id >> 5, c = id & 31;
            As[r][c] = A[(size_t)(rbase + r) * lda + k0 + c];
        }
#pragma unroll
        for (int i = 0; i < 8; ++i) {
            int id = tid + i * 256;
            int r = id >> 6, c = id & 63;
            Bs[r][c] = B[(size_t)(k0 + r) * ldb + cbase + c];
        }
        __syncthreads();
#pragma unroll 8
        for (int kk = 0; kk < 32; ++kk) {
            float a[4], bv[4];
#pragma unroll
            for (int i = 0; i < 4; ++i) a[i] = As[ty * 4 + i][kk];
#pragma unroll
            for (int j = 0; j < 4; ++j) bv[j] = Bs[kk][tx * 4 + j];
#pragma unroll
            for (int i = 0; i < 4; ++i)
#pragma unroll
                for (int j = 0; j < 4; ++j) acc[i][j] = fmaf(a[i], bv[j], acc[i][j]);
        }
    }
#pragma unroll
    for (int i = 0; i < 4; ++i) {
        int r = rbase + ty * 4 + i;
#pragma unroll
        for (int j = 0; j < 4; ++j) {
            int c = cbase + tx * 4 + j;
            float v = acc[i][j];
            if (accumulate) v += C[(size_t)r * ldc + c];
            C[(size_t)r * ldc + c] = v;
        }
    }
}

// ---------------- W2/W3/W4 -> fragment-packed bf16 hi/lo ----------------
// WF[(((t*3+l)*2+p)*8+nt)*4+ks][lane][i] ; B-frag: B[k][n], k=ks*32+(lane>>4)*8+i,
// n=nt*16+(lane&15)
__global__ __launch_bounds__(256) void k_prepw(const float* __restrict__ W2,
                                               const float* __restrict__ W3,
                                               const float* __restrict__ W4,
                                               u16* __restrict__ WF) {
    int bid = blockIdx.x;                  // 240 = 5*3*2*8
    int t = bid / 48;
    int l = (bid / 16) % 3;
    int p = (bid / 8) % 2;
    int nt = bid % 8;
    int tid = threadIdx.x;
    int ks = tid >> 6, lane = tid & 63;
    const float* W = (l == 0 ? W2 : l == 1 ? W3 : W4) + t * 16384;
    int n = nt * 16 + (lane & 15);
    int kb = ks * 32 + (lane >> 4) * 8;
    ushort8 o;
#pragma unroll
    for (int i = 0; i < 8; ++i) {
        float w = W[(size_t)(kb + i) * H + n];
        u16 h = f2bf(w);
        o[i] = (p == 0) ? h : f2bf(w - bf2f(h));
    }
    size_t base = ((size_t)((((t * 3 + l) * 2 + p) * 8 + nt) * 4 + ks) * 64 + lane) * 8;
    *reinterpret_cast<ushort8*>(WF + base) = o;
}

// ---------------- fused per-edge MLP: MFMA bf16 hi/lo split ----------------
__global__ __launch_bounds__(256, 2) void k_edge(const int* __restrict__ edges,
                                                 const float* __restrict__ P,
                                                 const float* __restrict__ Ps0,
                                                 const u16* __restrict__ WF,
                                                 const float* __restrict__ bb1,
                                                 const float* __restrict__ bb2,
                                                 const float* __restrict__ bb3,
                                                 const float* __restrict__ bb4,
                                                 float* __restrict__ lstm_in) {
    __shared__ u16 zhi[EB * H];
    __shared__ u16 zlo[EB * H];
    int tid = threadIdx.x;
    int w = tid >> 6, lane = tid & 63;
    int bid = blockIdx.x;
    int t = bid >> 10;            // 1024 tiles per type
    int tile = bid & 1023;
    int ebase = tile * EB;

    // ---- layer 1: z = relu(Ps[src]+Pd[dst]+b1), split to hi/lo bf16 in LDS ----
    {
        int row = tid >> 1, half = tid & 1;
        int e = ebase + row;
        int sn = edges[(t * 2 + 0) * NE + e];
        int dn = edges[(t * 2 + 1) * NE + e];
        const float* ps = (t == 0) ? Ps0 + (size_t)sn * H
                                   : P + (size_t)sn * 1152 + 640 + (t - 1) * H;
        const float* pd = P + (size_t)dn * 1152 + t * H;
        const float* bb = bb1 + t * H;
#pragma unroll
        for (int cc = 0; cc < 8; ++cc) {
            int c8 = half * 8 + cc;
            float4 a0 = reinterpret_cast<const float4*>(ps)[c8 * 2];
            float4 a1 = reinterpret_cast<const float4*>(ps)[c8 * 2 + 1];
            float4 d0 = reinterpret_cast<const float4*>(pd)[c8 * 2];
            float4 d1 = reinterpret_cast<const float4*>(pd)[c8 * 2 + 1];
            float4 e0 = reinterpret_cast<const float4*>(bb)[c8 * 2];
            float4 e1 = reinterpret_cast<const float4*>(bb)[c8 * 2 + 1];
            float v[8];
            v[0] = a0.x + d0.x + e0.x; v[1] = a0.y + d0.y + e0.y;
            v[2] = a0.z + d0.z + e0.z; v[3] = a0.w + d0.w + e0.w;
            v[4] = a1.x + d1.x + e1.x; v[5] = a1.y + d1.y + e1.y;
            v[6] = a1.z + d1.z + e1.z; v[7] = a1.w + d1.w + e1.w;
            ushort8 hh, ll;
#pragma unroll
            for (int i = 0; i < 8; ++i) {
                float x = fmaxf(v[i], 0.f);
                u16 h = f2bf(x);
                hh[i] = h;
                ll[i] = f2bf(x - bf2f(h));
            }
            int off = row * H + ((c8 ^ (row & 7)) * 8);   // swizzled 16B chunk
            *reinterpret_cast<ushort8*>(&zhi[off]) = hh;
            *reinterpret_cast<ushort8*>(&zlo[off]) = ll;
        }
    }
    // per-wave self-contained rows: wave w owns rows 32w..32w+31 -> no barriers

#define LOAD_A()                                                                  \
    _Pragma("unroll") for (int mt = 0; mt < 2; ++mt) {                            \
        int rr = (2 * w + mt) * 16 + (lane & 15);                                 \
        _Pragma("unroll") for (int ks = 0; ks < 4; ++ks) {                        \
            int off = rr * H + (((ks * 4 + (lane >> 4)) ^ (rr & 7)) * 8);         \
            Ah[mt][ks] = *reinterpret_cast<const short8*>(&zhi[off]);             \
            Al[mt][ks] = *reinterpret_cast<const short8*>(&zlo[off]);             \
        }                                                                         \
    }

#define MM(wfl)                                                                   \
    _Pragma("unroll") for (int nt = 0; nt < 8; ++nt) {                            \
        short8 Bh[4], Bl[4];                                                      \
        _Pragma("unroll") for (int ks = 0; ks < 4; ++ks) {                        \
            Bh[ks] = *reinterpret_cast<const short8*>((wfl) + ((nt * 4 + ks) * 64 + lane) * 8);        \
            Bl[ks] = *reinterpret_cast<const short8*>((wfl) + ((32 + nt * 4 + ks) * 64 + lane) * 8);   \
        }                                                                         \
        _Pragma("unroll") for (int mt = 0; mt < 2; ++mt)                          \
        _Pragma("unroll") for (int ks = 0; ks < 4; ++ks) {                        \
            acc[mt][nt] = __builtin_amdgcn_mfma_f32_16x16x32_bf16(Ah[mt][ks], Bh[ks], acc[mt][nt], 0, 0, 0); \
            acc[mt][nt] = __builtin_amdgcn_mfma_f32_16x16x32_bf16(Ah[mt][ks], Bl[ks], acc[mt][nt], 0, 0, 0); \
            acc[mt][nt] = __builtin_amdgcn_mfma_f32_16x16x32_bf16(Al[mt][ks], Bh[ks], acc[mt][nt], 0, 0, 0); \
        }                                                                         \
    }

#define WB_RELU(bptr)                                                             \
    _Pragma("unroll") for (int mt = 0; mt < 2; ++mt)                              \
    _Pragma("unroll") for (int nt = 0; nt < 8; ++nt) {                            \
        int col = nt * 16 + (lane & 15);                                          \
        float bi = (bptr)[col];                                                   \
        _Pragma("unroll") for (int r = 0; r < 4; ++r) {                           \
            int rr = (2 * w + mt) * 16 + (lane >> 4) * 4 + r;                     \
            float x = fmaxf(acc[mt][nt][r] + bi, 0.f);                            \
            u16 h = f2bf(x);                                                      \
            int off = rr * H + (((col >> 3) ^ (rr & 7)) * 8) + (col & 7);         \
            zhi[off] = h;                                                         \
            zlo[off] = f2bf(x - bf2f(h));                                         \
        }                                                                         \
    }

    short8 Ah[2][4], Al[2][4];
    const u16* wfbase = WF + (size_t)(t * 3) * 32768;   // per (t,layer): 2*8*4*512

    // ---- layer 2 ----
    {
        f32x4 acc[2][8] = {};
        LOAD_A();
        MM(wfbase);
        WB_RELU(bb2 + t * H);
    }
    // ---- layer 3 ----
    {
        f32x4 acc[2][8] = {};
        LOAD_A();
        MM(wfbase + 32768);
        WB_RELU(bb3 + t * H);
    }
    // ---- layer 4 + scatter ----
    {
        f32x4 acc[2][8] = {};
        LOAD_A();
        MM(wfbase + 65536);
        int dsts[2][4];
#pragma unroll
        for (int mt = 0; mt < 2; ++mt)
#pragma unroll
            for (int r = 0; r < 4; ++r)
                dsts[mt][r] = edges[(t * 2 + 1) * NE + ebase +
                                    (2 * w + mt) * 16 + (lane >> 4) * 4 + r];
        const float* bb = bb4 + t * H;
#pragma unroll
        for (int mt = 0; mt < 2; ++mt)
#pragma unroll
            for (int nt = 0; nt < 8; ++nt) {
                int col = nt * 16 + (lane & 15);
                float bi = bb[col];
#pragma unroll
                for (int r = 0; r < 4; ++r)
                    atomicAdd(lstm_in + (size_t)dsts[mt][r] * LIN_W + H + t * H + col,
                              acc[mt][nt][r] + bi);
            }
    }
#undef LOAD_A
#undef MM
#undef WB_RELU
}

// ---------------- LSTM pointwise ----------------
__global__ __launch_bounds__(256) void k_lstm(const float* __restrict__ gates,
                                              float* __restrict__ cst,
                                              float* __restrict__ rnn_h) {
    int idx = blockIdx.x * 256 + threadIdx.x;   // NCELL*H
    int row = idx >> 7, cc = idx & 127;
    const float* g = gates + (size_t)row * G4;
    float ig = g[cc], fg = g[128 + cc], gg = g[256 + cc], og = g[384 + cc];
    float c_old = cst[idx];
    float i_s = 1.f / (1.f + expf(-ig));
    float f_s = 1.f / (1.f + expf(-fg));
    float o_s = 1.f / (1.f + expf(-og));
    float c_new = f_s * c_old + i_s * tanhf(gg);
    float h_new = o_s * tanhf(c_new);
    cst[idx] = c_new;
    rnn_h[idx] = h_new;
}

// ---------------- logits ----------------
__global__ __launch_bounds__(256) void k_logits(const float* __restrict__ h,
                                                const float* __restrict__ oemb,
                                                float* __restrict__ out) {
    __shared__ float oe[17][129];
    int b = blockIdx.x, tid = threadIdx.x;
    for (int id = tid; id < 17 * 128; id += 256) {
        int r = id >> 7, c = id & 127;
        oe[r][c] = oemb[(b * 17 + r) * H + c];
    }
    __syncthreads();
    const float* hr = h + (size_t)(b * 256 + tid) * H;
    float acc[17] = {};
    for (int v = 0; v < 32; ++v) {
        float4 hv = reinterpret_cast<const float4*>(hr)[v];
#pragma unroll
        for (int cls = 0; cls < 17; ++cls) {
            acc[cls] = fmaf(hv.x, oe[cls][v * 4 + 0],
                       fmaf(hv.y, oe[cls][v * 4 + 1],
                       fmaf(hv.z, oe[cls][v * 4 + 2],
                       fmaf(hv.w, oe[cls][v * 4 + 3], acc[cls]))));
        }
    }
    float* op = out + (size_t)(b * 256 + tid) * 17;
#pragma unroll
    for (int cls = 0; cls < 17; ++cls) op[cls] = acc[cls];
}

extern "C" void kernel_launch(void* const* d_in, const int* in_sizes, int n_in,
                              void* d_out, int out_size, void* d_ws, size_t ws_size,
                              hipStream_t stream) {
    (void)in_sizes; (void)n_in; (void)out_size; (void)ws_size;
    const int*   edges = (const int*)d_in[0];
    const int*   q     = (const int*)d_in[1];
    const float* emb   = (const float*)d_in[2];
    const float* oemb  = (const float*)d_in[3];
    const float* W1    = (const float*)d_in[4];
    const float* b1    = (const float*)d_in[5];
    const float* W2    = (const float*)d_in[6];
    const float* b2    = (const float*)d_in[7];
    const float* W3    = (const float*)d_in[8];
    const float* b3    = (const float*)d_in[9];
    const float* W4    = (const float*)d_in[10];
    const float* b4    = (const float*)d_in[11];
    const float* Wih   = (const float*)d_in[12];
    const float* Whh   = (const float*)d_in[13];
    float* out = (float*)d_out;

    float* ws      = (float*)d_ws;
    float* lstm_in = ws;                              // 16384*768
    float* hx      = lstm_in + (size_t)NCELL * LIN_W; // 16384*128
    float* rnn_h   = hx + (size_t)NCELL * H;
    float* cst     = rnn_h + (size_t)NCELL * H;
    float* P       = cst + (size_t)NCELL * H;         // 16384*1152
    float* gates   = P;                               // alias (P dead when gates live)
    float* Ps0     = P + (size_t)NCELL * 1152;        // 1088*128
    float* avg     = Ps0 + (size_t)NCLU * H;          // 64*128
    u16*   WF      = (u16*)(avg + 64 * H);            // 983040 u16 = 1.92MB

    k_avg<<<64, 128, 0, stream>>>(emb, avg);
    k_init<<<2048, 256, 0, stream>>>(q, emb, avg, lstm_in, hx, rnn_h, cst);
    k_prepw<<<240, 256, 0, stream>>>(W2, W3, W4, WF);
    {
        dim3 g0(17, 2);
        k_gemm<<<g0, 256, 0, stream>>>(emb, H, W1, H, Ps0, H, H, 0);
    }

    for (int s = 0; s < SSTEPS; ++s) {
        k_zeromsg<<<10240, 256, 0, stream>>>(lstm_in);
        const float* hcur = (s == 0) ? hx : rnn_h;
        dim3 gp(256, 2);
        for (int t = 0; t < 5; ++t)
            k_gemm<<<gp, 256, 0, stream>>>(hcur, H, W1 + t * 32768 + 16384, H,
                                           P + t * 128, 1152, H, 0);
        for (int t = 1; t < 5; ++t)
            k_gemm<<<gp, 256, 0, stream>>>(hcur, H, W1 + t * 32768, H,
                                           P + 640 + (t - 1) * 128, 1152, H, 0);
        k_edge<<<NT * (NE / EB), 256, 0, stream>>>(edges, P, Ps0, WF, b1, b2, b3,
                                                   b4, lstm_in);
        dim3 gg(256, 8);
        k_gemm<<<gg, 256, 0, stream>>>(lstm_in, LIN_W, Wih, G4, gates, G4, LIN_W, 0);
        if (s > 0)
            k_gemm<<<gg, 256, 0, stream>>>(rnn_h, H, Whh, G4, gates, G4, H, 1);
        k_lstm<<<8192, 256, 0, stream>>>(gates, cst, rnn_h);
        k_logits<<<64, 256, 0, stream>>>(rnn_h, oemb, out + (size_t)s * NCELL * 17);
    }
}

// Round 3
// 1642.402 us; speedup vs baseline: 5.1288x; 1.5975x over previous
//
#include <hip/hip_runtime.h>
#include <math.h>

#define H 128
#define SSTEPS 3
#define NE 131072
#define NT 5
#define NCELL 16384
#define NCLU 1088
#define G4 512
#define MSGW 640     // 5*H message block
#define AKT 28       // Apack kt count (896 K-cols / 32)
#define EB 128

typedef unsigned short u16;
typedef __attribute__((ext_vector_type(8))) short short8;
typedef __attribute__((ext_vector_type(8))) unsigned short ushort8;
typedef __attribute__((ext_vector_type(4))) float f32x4;

__device__ __forceinline__ u16 f2bf(float f) {
    unsigned int u = __float_as_uint(f);
    u += 0x7fffu + ((u >> 16) & 1u);
    return (u16)(u >> 16);
}
__device__ __forceinline__ float bf2f(u16 h) {
    return __uint_as_float(((unsigned int)h) << 16);
}

// ---------------- avg of class embeddings 1..16 per batch ----------------
__global__ __launch_bounds__(128) void k_avg(const float* __restrict__ emb,
                                             float* __restrict__ avg) {
    int b = blockIdx.x, hc = threadIdx.x;
    float s = 0.f;
#pragma unroll
    for (int r = 1; r <= 16; ++r) s += emb[(b * 17 + r) * H + hc];
    avg[b * H + hc] = s * (1.0f / 16.0f);
}

// ---------------- init: cell_x -> Apack kt 0:4 (hi/lo); zero rnn_h, cst ----------------
__global__ __launch_bounds__(256) void k_init(const int* __restrict__ q,
                                              const float* __restrict__ emb,
                                              const float* __restrict__ avg,
                                              u16* __restrict__ Ap, size_t aplane,
                                              float* __restrict__ rnn_h,
                                              float* __restrict__ cst) {
    __shared__ float sx[16][132];
    int mtile = blockIdx.x, tid = threadIdx.x;
#pragma unroll
    for (int e = 0; e < 8; ++e) {
        int idx = e * 256 + tid;
        int row = idx >> 7, c = idx & 127;
        int grow = mtile * 16 + row;
        int b = grow >> 8;
        int qi = q[grow];
        const float* src = (qi == 0) ? (avg + b * H) : (emb + (b * 17 + qi) * H);
        float v = src[c];
        sx[row][c] = v;
        rnn_h[(size_t)grow * H + c] = 0.f;
        cst[(size_t)grow * H + c] = 0.f;
    }
    __syncthreads();
    int kt = tid >> 6, lane = tid & 63;
    int row = lane & 15, c0 = kt * 32 + ((lane >> 4) << 3);
    ushort8 hh, ll;
#pragma unroll
    for (int i = 0; i < 8; ++i) {
        float x = sx[row][c0 + i];
        u16 h = f2bf(x);
        hh[i] = h;
        ll[i] = f2bf(x - bf2f(h));
    }
    size_t fo = ((size_t)(mtile * AKT + kt) * 64 + lane) * 8;
    *reinterpret_cast<ushort8*>(Ap + fo) = hh;
    *reinterpret_cast<ushort8*>(Ap + aplane + fo) = ll;
}

// ---------------- zero msg buffer ----------------
__global__ __launch_bounds__(256) void k_zeromsg(float* __restrict__ msg) {
    int idx = blockIdx.x * 256 + threadIdx.x;   // NCELL*MSGW/4
    reinterpret_cast<float4*>(msg)[idx] = make_float4(0.f, 0.f, 0.f, 0.f);
}

// ---------------- fp32 GEMM -> bf16 out (Ps0 only; tiny) ----------------
__global__ __launch_bounds__(256) void k_gemm32(const float* __restrict__ A, int lda,
                                                const float* __restrict__ B, int ldb,
                                                u16* __restrict__ C, int ldc, int K) {
    __shared__ float As[64][33];
    __shared__ float Bs[32][64];
    int tid = threadIdx.x;
    int ty = tid >> 4, tx = tid & 15;
    int rbase = blockIdx.x * 64, cbase = blockIdx.y * 64;
    float acc[4][4] = {};
    for (int k0 = 0; k0 < K; k0 += 32) {
        __syncthreads();
#pragma unroll
        for (int i = 0; i < 8; ++i) {
            int id = tid + i * 256;
            int r = id >> 5, c = id & 31;
            As[r][c] = A[(size_t)(rbase + r) * lda + k0 + c];
        }
#pragma unroll
        for (int i = 0; i < 8; ++i) {
            int id = tid + i * 256;
            int r = id >> 6, c = id & 63;
            Bs[r][c] = B[(size_t)(k0 + r) * ldb + cbase + c];
        }
        __syncthreads();
#pragma unroll 8
        for (int kk = 0; kk < 32; ++kk) {
            float a[4], bv[4];
#pragma unroll
            for (int i = 0; i < 4; ++i) a[i] = As[ty * 4 + i][kk];
#pragma unroll
            for (int j = 0; j < 4; ++j) bv[j] = Bs[kk][tx * 4 + j];
#pragma unroll
            for (int i = 0; i < 4; ++i)
#pragma unroll
                for (int j = 0; j < 4; ++j) acc[i][j] = fmaf(a[i], bv[j], acc[i][j]);
        }
    }
#pragma unroll
    for (int i = 0; i < 4; ++i)
#pragma unroll
        for (int j = 0; j < 4; ++j)
            C[(size_t)(rbase + ty * 4 + i) * ldc + cbase + tx * 4 + j] = f2bf(acc[i][j]);
}

// ---------------- W2/W3/W4 -> fragment-packed bf16 hi/lo (unchanged layout) ----------------
__global__ __launch_bounds__(256) void k_prepw(const float* __restrict__ W2,
                                               const float* __restrict__ W3,
                                               const float* __restrict__ W4,
                                               u16* __restrict__ WF) {
    int bid = blockIdx.x;                  // 240 = 5*3*2*8
    int t = bid / 48;
    int l = (bid / 16) % 3;
    int p = (bid / 8) % 2;
    int nt = bid % 8;
    int tid = threadIdx.x;
    int ks = tid >> 6, lane = tid & 63;
    const float* W = (l == 0 ? W2 : l == 1 ? W3 : W4) + t * 16384;
    int n = nt * 16 + (lane & 15);
    int kb = ks * 32 + (lane >> 4) * 8;
    ushort8 o;
#pragma unroll
    for (int i = 0; i < 8; ++i) {
        float w = W[(size_t)(kb + i) * H + n];
        u16 h = f2bf(w);
        o[i] = (p == 0) ? h : f2bf(w - bf2f(h));
    }
    size_t base = ((size_t)((((t * 3 + l) * 2 + p) * 8 + nt) * 4 + ks) * 64 + lane) * 8;
    *reinterpret_cast<ushort8*>(WF + base) = o;
}

// ---------------- pack [Wih;Whh] -> B-frags hi/lo ----------------
__global__ __launch_bounds__(256) void k_packBw(const float* __restrict__ Wih,
                                                const float* __restrict__ Whh,
                                                u16* __restrict__ Bw, size_t bplane) {
    int nt = blockIdx.x;                           // 32
    int kt = blockIdx.y * 4 + (threadIdx.x >> 6);  // grid.y=7 -> 0..27
    int lane = threadIdx.x & 63;
    int n = nt * 16 + (lane & 15);
    int k0 = kt * 32 + ((lane >> 4) << 3);
    ushort8 hh, ll;
#pragma unroll
    for (int i = 0; i < 8; ++i) {
        int k = k0 + i;
        float wv = (k < 768) ? Wih[(size_t)k * G4 + n] : Whh[(size_t)(k - 768) * G4 + n];
        u16 h = f2bf(wv);
        hh[i] = h;
        ll[i] = f2bf(wv - bf2f(h));
    }
    size_t fo = ((size_t)(nt * AKT + kt) * 64 + lane) * 8;
    *reinterpret_cast<ushort8*>(Bw + fo) = hh;
    *reinterpret_cast<ushort8*>(Bw + bplane + fo) = ll;
}

// ---------------- pack projection weights (from W1) -> B-frags hi/lo ----------------
// Bp cols: [0:640) = W1d_t (rows 128:256), [640:1152) = W1s_t t=1..4 (rows 0:128)
__global__ __launch_bounds__(256) void k_packBp(const float* __restrict__ W1,
                                                u16* __restrict__ Bp, size_t bplane) {
    int nt = blockIdx.x;               // 72
    int kt = threadIdx.x >> 6;         // 0..3
    int lane = threadIdx.x & 63;
    int n = nt * 16 + (lane & 15);
    int k0 = kt * 32 + ((lane >> 4) << 3);
    int t, roff, j;
    if (n < 640) { t = n >> 7; j = n & 127; roff = 128; }
    else { int m = n - 640; t = (m >> 7) + 1; j = m & 127; roff = 0; }
    ushort8 hh, ll;
#pragma unroll
    for (int i = 0; i < 8; ++i) {
        float wv = W1[((size_t)t * 256 + roff + k0 + i) * H + j];
        u16 h = f2bf(wv);
        hh[i] = h;
        ll[i] = f2bf(wv - bf2f(h));
    }
    size_t fo = ((size_t)(nt * 4 + kt) * 64 + lane) * 8;
    *reinterpret_cast<ushort8*>(Bp + fo) = hh;
    *reinterpret_cast<ushort8*>(Bp + bplane + fo) = ll;
}

// ---------------- pack msg fp32 -> Apack kt 4:24 hi/lo ----------------
__global__ __launch_bounds__(256) void k_packmsg(const float* __restrict__ msg,
                                                 u16* __restrict__ Ap, size_t aplane) {
    int mtile = blockIdx.x;
    int ktl = blockIdx.y * 4 + (threadIdx.x >> 6);   // 0..19
    int lane = threadIdx.x & 63;
    int row = mtile * 16 + (lane & 15);
    int c0 = ktl * 32 + ((lane >> 4) << 3);
    const float* src = msg + (size_t)row * MSGW + c0;
    ushort8 hh, ll;
#pragma unroll
    for (int i = 0; i < 8; ++i) {
        float x = src[i];
        u16 h = f2bf(x);
        hh[i] = h;
        ll[i] = f2bf(x - bf2f(h));
    }
    size_t fo = ((size_t)(mtile * AKT + 4 + ktl) * 64 + lane) * 8;
    *reinterpret_cast<ushort8*>(Ap + fo) = hh;
    *reinterpret_cast<ushort8*>(Ap + aplane + fo) = ll;
}

// ---------------- MFMA GEMM, 3-term split bf16, frag inputs, no LDS ----------------
// C[M,N] (fp32 Cf or bf16 Ch) ; A frags at mtile*AKT + aktbase + kk ; B frags at nt*bKT + kk
__global__ __launch_bounds__(256) void k_gemm_bf(const u16* __restrict__ Ap, size_t aplane,
                                                 int aktbase,
                                                 const u16* __restrict__ Bp, size_t bplane,
                                                 int bKT, int nkt,
                                                 float* __restrict__ Cf, u16* __restrict__ Ch,
                                                 int ldc) {
    int tid = threadIdx.x;
    int w = tid >> 6, lane = tid & 63;
    int wr = w >> 1, wc = w & 1;
    int mtb = blockIdx.x * 8 + wr * 4;
    int ntb = blockIdx.y * 8 + wc * 4;
    f32x4 acc[4][4] = {};
    for (int kk = 0; kk < nkt; ++kk) {
        short8 Ah[4], Al[4], Bh[4], Bl[4];
#pragma unroll
        for (int m = 0; m < 4; ++m) {
            size_t fo = ((size_t)((mtb + m) * AKT + aktbase + kk) * 64 + lane) * 8;
            Ah[m] = *reinterpret_cast<const short8*>(Ap + fo);
            Al[m] = *reinterpret_cast<const short8*>(Ap + aplane + fo);
        }
#pragma unroll
        for (int n = 0; n < 4; ++n) {
            size_t fo = ((size_t)((ntb + n) * bKT + kk) * 64 + lane) * 8;
            Bh[n] = *reinterpret_cast<const short8*>(Bp + fo);
            Bl[n] = *reinterpret_cast<const short8*>(Bp + bplane + fo);
        }
#pragma unroll
        for (int m = 0; m < 4; ++m)
#pragma unroll
            for (int n = 0; n < 4; ++n) {
                acc[m][n] = __builtin_amdgcn_mfma_f32_16x16x32_bf16(Ah[m], Bh[n], acc[m][n], 0, 0, 0);
                acc[m][n] = __builtin_amdgcn_mfma_f32_16x16x32_bf16(Ah[m], Bl[n], acc[m][n], 0, 0, 0);
                acc[m][n] = __builtin_amdgcn_mfma_f32_16x16x32_bf16(Al[m], Bh[n], acc[m][n], 0, 0, 0);
            }
    }
#pragma unroll
    for (int m = 0; m < 4; ++m)
#pragma unroll
        for (int r = 0; r < 4; ++r) {
            int row = (mtb + m) * 16 + (lane >> 4) * 4 + r;
#pragma unroll
            for (int n = 0; n < 4; ++n) {
                int col = (ntb + n) * 16 + (lane & 15);
                float v = acc[m][n][r];
                if (Ch) Ch[(size_t)row * ldc + col] = f2bf(v);
                else Cf[(size_t)row * ldc + col] = v;
            }
        }
}

// ---------------- fused per-edge MLP: col-split waves, A-hi * (B-hi+B-lo) ----------------
__global__ __launch_bounds__(256, 3) void k_edge(const int* __restrict__ edges,
                                                 const u16* __restrict__ P,
                                                 const u16* __restrict__ Ps0,
                                                 const u16* __restrict__ WF,
                                                 const float* __restrict__ bb1,
                                                 const float* __restrict__ bb2,
                                                 const float* __restrict__ bb3,
                                                 const float* __restrict__ bb4,
                                                 float* __restrict__ msg) {
    __shared__ u16 zh[EB * H];    // 32KB, 16B-chunk XOR swizzle
    __shared__ int sdst[EB];
    int tid = threadIdx.x;
    int w = tid >> 6, lane = tid & 63;
    int bid = blockIdx.x;
    int t = bid >> 10, tile = bid & 1023;
    int ebase = tile * EB;

    // ---- layer 1 ----
    {
        int row = tid >> 1, half = tid & 1;
        int e = ebase + row;
        int sn = edges[(t * 2) * NE + e];
        int dn = edges[(t * 2 + 1) * NE + e];
        if (half == 0) sdst[row] = dn;
        const u16* ps = (t == 0) ? Ps0 + (size_t)sn * H
                                 : P + (size_t)sn * 1152 + 640 + (t - 1) * H;
        const u16* pd = P + (size_t)dn * 1152 + t * H;
        const float* bb = bb1 + t * H;
#pragma unroll
        for (int cc = 0; cc < 8; ++cc) {
            int c8 = half * 8 + cc;
            ushort8 a = *reinterpret_cast<const ushort8*>(ps + c8 * 8);
            ushort8 d = *reinterpret_cast<const ushort8*>(pd + c8 * 8);
            float4 b0 = *reinterpret_cast<const float4*>(bb + c8 * 8);
            float4 b1v = *reinterpret_cast<const float4*>(bb + c8 * 8 + 4);
            float bv[8] = {b0.x, b0.y, b0.z, b0.w, b1v.x, b1v.y, b1v.z, b1v.w};
            ushort8 hh;
#pragma unroll
            for (int i = 0; i < 8; ++i)
                hh[i] = f2bf(fmaxf(bf2f(a[i]) + bf2f(d[i]) + bv[i], 0.f));
            *reinterpret_cast<ushort8*>(&zh[row * H + ((c8 ^ (row & 7)) << 3)]) = hh;
        }
    }
    __syncthreads();

    const u16* wfbase = WF + (size_t)(t * 3) * 32768;
    f32x4 acc[8][2];
    short8 Bh[2][4], Bl[2][4];

    for (int l = 0; l < 3; ++l) {
        const u16* wl = wfbase + l * 32768;
#pragma unroll
        for (int ng = 0; ng < 2; ++ng)
#pragma unroll
            for (int ks = 0; ks < 4; ++ks) {
                int nt = 2 * w + ng;
                Bh[ng][ks] = *reinterpret_cast<const short8*>(wl + ((nt * 4 + ks) * 64 + lane) * 8);
                Bl[ng][ks] = *reinterpret_cast<const short8*>(wl + ((32 + nt * 4 + ks) * 64 + lane) * 8);
            }
#pragma unroll
        for (int mt = 0; mt < 8; ++mt)
#pragma unroll
            for (int ng = 0; ng < 2; ++ng)
                acc[mt][ng] = (f32x4){0.f, 0.f, 0.f, 0.f};
#pragma unroll
        for (int mt = 0; mt < 8; ++mt) {
            short8 Ah[4];
            int rr = mt * 16 + (lane & 15);
#pragma unroll
            for (int ks = 0; ks < 4; ++ks) {
                int ch = ks * 4 + (lane >> 4);
                Ah[ks] = *reinterpret_cast<const short8*>(&zh[rr * H + ((ch ^ (rr & 7)) << 3)]);
            }
#pragma unroll
            for (int ng = 0; ng < 2; ++ng)
#pragma unroll
                for (int ks = 0; ks < 4; ++ks) {
                    acc[mt][ng] = __builtin_amdgcn_mfma_f32_16x16x32_bf16(Ah[ks], Bh[ng][ks], acc[mt][ng], 0, 0, 0);
                    acc[mt][ng] = __builtin_amdgcn_mfma_f32_16x16x32_bf16(Ah[ks], Bl[ng][ks], acc[mt][ng], 0, 0, 0);
                }
        }
        if (l < 2) {
            __syncthreads();   // all reads of zh done
            const float* bb = (l == 0 ? bb2 : bb3) + t * H;
            float bi[2];
#pragma unroll
            for (int ng = 0; ng < 2; ++ng) bi[ng] = bb[(2 * w + ng) * 16 + (lane & 15)];
#pragma unroll
            for (int mt = 0; mt < 8; ++mt)
#pragma unroll
                for (int ng = 0; ng < 2; ++ng) {
                    int col = (2 * w + ng) * 16 + (lane & 15);
#pragma unroll
                    for (int r = 0; r < 4; ++r) {
                        int rr = mt * 16 + (lane >> 4) * 4 + r;
                        float x = fmaxf(acc[mt][ng][r] + bi[ng], 0.f);
                        zh[rr * H + (((col >> 3) ^ (rr & 7)) << 3) + (col & 7)] = f2bf(x);
                    }
                }
            __syncthreads();   // writes visible
        } else {
            const float* bb = bb4 + t * H;
            float bi[2];
#pragma unroll
            for (int ng = 0; ng < 2; ++ng) bi[ng] = bb[(2 * w + ng) * 16 + (lane & 15)];
#pragma unroll
            for (int mt = 0; mt < 8; ++mt)
#pragma unroll
                for (int ng = 0; ng < 2; ++ng) {
                    int col = (2 * w + ng) * 16 + (lane & 15);
#pragma unroll
                    for (int r = 0; r < 4; ++r) {
                        int rr = mt * 16 + (lane >> 4) * 4 + r;
                        atomicAdd(msg + (size_t)sdst[rr] * MSGW + t * H + col,
                                  acc[mt][ng][r] + bi[ng]);
                    }
                }
        }
    }
}

// ---------------- LSTM pointwise + h frag pack (kt 24:28) ----------------
__global__ __launch_bounds__(256) void k_lstm(const float* __restrict__ gates,
                                              float* __restrict__ cst,
                                              float* __restrict__ rnn_h,
                                              u16* __restrict__ Ap, size_t aplane) {
    __shared__ float sh[16][132];
    int mtile = blockIdx.x, tid = threadIdx.x;
#pragma unroll
    for (int e = 0; e < 8; ++e) {
        int idx = e * 256 + tid;
        int row = idx >> 7, c = idx & 127;
        int grow = mtile * 16 + row;
        const float* g = gates + (size_t)grow * G4;
        float ig = g[c], fg = g[128 + c], gg = g[256 + c], og = g[384 + c];
        size_t ci = (size_t)grow * H + c;
        float c_old = cst[ci];
        float i_s = 1.f / (1.f + expf(-ig));
        float f_s = 1.f / (1.f + expf(-fg));
        float o_s = 1.f / (1.f + expf(-og));
        float c_new = f_s * c_old + i_s * tanhf(gg);
        float h_new = o_s * tanhf(c_new);
        cst[ci] = c_new;
        rnn_h[ci] = h_new;
        sh[row][c] = h_new;
    }
    __syncthreads();
    int kt = tid >> 6, lane = tid & 63;
    int row = lane & 15, c0 = kt * 32 + ((lane >> 4) << 3);
    ushort8 hh, ll;
#pragma unroll
    for (int i = 0; i < 8; ++i) {
        float x = sh[row][c0 + i];
        u16 h = f2bf(x);
        hh[i] = h;
        ll[i] = f2bf(x - bf2f(h));
    }
    size_t fo = ((size_t)(mtile * AKT + 24 + kt) * 64 + lane) * 8;
    *reinterpret_cast<ushort8*>(Ap + fo) = hh;
    *reinterpret_cast<ushort8*>(Ap + aplane + fo) = ll;
}

// ---------------- logits ----------------
__global__ __launch_bounds__(256) void k_logits(const float* __restrict__ h,
                                                const float* __restrict__ oemb,
                                                float* __restrict__ out) {
    __shared__ float oe[17][129];
    int b = blockIdx.x, tid = threadIdx.x;
    for (int id = tid; id < 17 * 128; id += 256) {
        int r = id >> 7, c = id & 127;
        oe[r][c] = oemb[(b * 17 + r) * H + c];
    }
    __syncthreads();
    const float* hr = h + (size_t)(b * 256 + tid) * H;
    float acc[17] = {};
    for (int v = 0; v < 32; ++v) {
        float4 hv = reinterpret_cast<const float4*>(hr)[v];
#pragma unroll
        for (int cls = 0; cls < 17; ++cls) {
            acc[cls] = fmaf(hv.x, oe[cls][v * 4 + 0],
                       fmaf(hv.y, oe[cls][v * 4 + 1],
                       fmaf(hv.z, oe[cls][v * 4 + 2],
                       fmaf(hv.w, oe[cls][v * 4 + 3], acc[cls]))));
        }
    }
    float* op = out + (size_t)(b * 256 + tid) * 17;
#pragma unroll
    for (int cls = 0; cls < 17; ++cls) op[cls] = acc[cls];
}

extern "C" void kernel_launch(void* const* d_in, const int* in_sizes, int n_in,
                              void* d_out, int out_size, void* d_ws, size_t ws_size,
                              hipStream_t stream) {
    (void)in_sizes; (void)n_in; (void)out_size; (void)ws_size;
    const int*   edges = (const int*)d_in[0];
    const int*   q     = (const int*)d_in[1];
    const float* emb   = (const float*)d_in[2];
    const float* oemb  = (const float*)d_in[3];
    const float* W1    = (const float*)d_in[4];
    const float* b1    = (const float*)d_in[5];
    const float* W2    = (const float*)d_in[6];
    const float* b2    = (const float*)d_in[7];
    const float* W3    = (const float*)d_in[8];
    const float* b3    = (const float*)d_in[9];
    const float* W4    = (const float*)d_in[10];
    const float* b4    = (const float*)d_in[11];
    const float* Wih   = (const float*)d_in[12];
    const float* Whh   = (const float*)d_in[13];
    float* out = (float*)d_out;

    // ---- workspace layout (bytes, 256-aligned) ----
    char* wsp = (char*)d_ws;
    size_t off = 0;
    auto alloc = [&](size_t bytes) { void* p = wsp + off; off = (off + bytes + 255) & ~(size_t)255; return p; };
    float* msg    = (float*)alloc((size_t)NCELL * MSGW * 4);        // 41.9MB
    u16*   P      = (u16*)  alloc((size_t)NCELL * 1152 * 2);        // 37.7MB (gates aliases)
    float* gates  = (float*)P;                                      // 33.5MB fp32, P dead then
    float* rnn_h  = (float*)alloc((size_t)NCELL * H * 4);
    float* cst    = (float*)alloc((size_t)NCELL * H * 4);
    u16*   Ps0    = (u16*)  alloc((size_t)NCLU * H * 2);
    float* avg    = (float*)alloc((size_t)64 * H * 4);
    size_t aplane = (size_t)NCELL * 896;                            // elems per plane
    u16*   Ap     = (u16*)  alloc(aplane * 2 * 2);                  // 58.7MB
    u16*   WF     = (u16*)  alloc((size_t)983040 * 2);
    size_t bwpl   = (size_t)512 * 896;
    u16*   Bw     = (u16*)  alloc(bwpl * 2 * 2);
    size_t bppl   = (size_t)1152 * 128;
    u16*   Bp     = (u16*)  alloc(bppl * 2 * 2);

    // ---- one-time prep ----
    k_avg<<<64, 128, 0, stream>>>(emb, avg);
    k_init<<<1024, 256, 0, stream>>>(q, emb, avg, Ap, aplane, rnn_h, cst);
    k_prepw<<<240, 256, 0, stream>>>(W2, W3, W4, WF);
    {
        dim3 g(32, 7);
        k_packBw<<<g, 256, 0, stream>>>(Wih, Whh, Bw, bwpl);
    }
    k_packBp<<<72, 256, 0, stream>>>(W1, Bp, bppl);
    {
        dim3 g0(17, 2);
        k_gemm32<<<g0, 256, 0, stream>>>(emb, H, W1, H, Ps0, H, H);
    }

    for (int s = 0; s < SSTEPS; ++s) {
        k_zeromsg<<<NCELL * MSGW / 4 / 256, 256, 0, stream>>>(msg);
        // P = h @ Wproj  (bf16 out) ; A-frags: kt 0:4 (cell_x) at s=0 else kt 24:28 (h)
        {
            dim3 g(128, 9);
            k_gemm_bf<<<g, 256, 0, stream>>>(Ap, aplane, (s == 0) ? 0 : 24,
                                             Bp, bppl, 4, 4, nullptr, P, 1152);
        }
        k_edge<<<NT * (NE / EB), 256, 0, stream>>>(edges, P, Ps0, WF, b1, b2, b3, b4, msg);
        {
            dim3 g(1024, 5);
            k_packmsg<<<g, 256, 0, stream>>>(msg, Ap, aplane);
        }
        // gates = [cell_x, msg, h] @ [Wih; Whh]  (K = 768 at s=0, 896 else)
        {
            dim3 g(128, 4);
            k_gemm_bf<<<g, 256, 0, stream>>>(Ap, aplane, 0, Bw, bwpl, AKT,
                                             (s == 0) ? 24 : 28, gates, nullptr, G4);
        }
        k_lstm<<<1024, 256, 0, stream>>>(gates, cst, rnn_h, Ap, aplane);
        k_logits<<<64, 256, 0, stream>>>(rnn_h, oemb, out + (size_t)s * NCELL * 17);
    }
}